// Round 4
// baseline (256.698 us; speedup 1.0000x reference)
//
#include <hip/hip_runtime.h>
#include <hip/hip_cooperative_groups.h>
#include <math.h>

namespace cg = cooperative_groups;

#define BATCH   64
#define CH      256
#define RCH     64
#define HW      3136          // 56*56 floats per plane
#define HWF4    784           // f4 per plane (3136/4)
#define NPLANES (BATCH * CH)  // 16384
#define NBLK    256           // one block per CU (cooperative)
#define NTHR    1024          // 16 waves/block
#define PPB     64            // planes per block (16384/256)
#define PPW     4             // planes per wave (64/16 waves)
#define NREG    5             // f4 wave-strides held in registers per plane
#define LDSPL   63            // planes whose stride-5 is LDS-held (fits 64KB)

typedef float f4 __attribute__((ext_vector_type(4)));

// Single persistent cooperative kernel:
//  phase 1: stream x once; accumulate plane sums; keep strides 0..4 in regs,
//           stride 5 in LDS (63/64 planes); strides 6..12 discarded.
//  grid sync.
//  phase 2: per-block excite (reads s for its batch from ws, computes h then
//           g for its 64 channels — redundant across 4 blocks, trivial cost).
//  phase 3: scale: regs/LDS for held 49%, re-read HBM for the rest; nt stores.
__global__ __launch_bounds__(NTHR, 4)
void se_fused(const float* __restrict__ x,
              const float* __restrict__ w1,
              const float* __restrict__ b1,
              const float* __restrict__ w2,
              const float* __restrict__ b2,
              float* __restrict__ out,
              float* __restrict__ s_ws) {
    const int bid   = blockIdx.x;
    const int tid   = threadIdx.x;
    const int w     = tid >> 6;
    const int lane  = tid & 63;
    const int batch = bid >> 2;          // 4 blocks per batch
    const int cbase = (bid & 3) * PPB;   // channel base of this block

    __shared__ f4    lds4[LDSPL * 64];   // 64512 B
    __shared__ float h_lds[RCH];         // 256 B
    __shared__ float g_lds[PPB];         // 256 B   (total 65024 <= 64KB)

    f4 hold[PPW][NREG];                  // 80 data VGPRs, all static-indexed
    float psum[PPW];

    const f4* __restrict__ xb = (const f4*)x + (size_t)(bid * PPB) * HWF4;

    // ---------------- phase 1: pool + cache ----------------
    #pragma unroll
    for (int q = 0; q < PPW; ++q) {
        const int pl = w * PPW + q;                    // plane_local 0..63
        const f4* __restrict__ xp = xb + (size_t)pl * HWF4;
        float acc = 0.0f;
        #pragma unroll
        for (int st = 0; st < NREG; ++st) {
            f4 v = xp[st * 64 + lane];
            hold[q][st] = v;
            acc += (v.x + v.y) + (v.z + v.w);
        }
        {
            f4 v = xp[NREG * 64 + lane];               // stride 5 -> LDS
            if (pl < LDSPL) lds4[pl * 64 + lane] = v;
            acc += (v.x + v.y) + (v.z + v.w);
        }
        #pragma unroll
        for (int st = NREG + 1; st < 12; ++st) {       // strides 6..11
            f4 v = xp[st * 64 + lane];
            acc += (v.x + v.y) + (v.z + v.w);
        }
        if (lane < 16) {                               // tail: 784 = 12*64+16
            f4 v = xp[768 + lane];
            acc += (v.x + v.y) + (v.z + v.w);
        }
        psum[q] = acc;
    }
    #pragma unroll
    for (int q = 0; q < PPW; ++q) {
        float a = psum[q];
        #pragma unroll
        for (int off = 32; off > 0; off >>= 1)
            a += __shfl_down(a, off, 64);
        if (lane == 0)
            s_ws[bid * PPB + w * PPW + q] = a * (1.0f / (float)HW);
    }

    __threadfence();
    cg::this_grid().sync();

    // ---------------- phase 2: excite (per block, redundant x4) ----------
    if (tid < RCH) {
        float acc = b1[tid];
        const float* __restrict__ wr = w1 + tid * CH;
        const float* __restrict__ sb = s_ws + batch * CH;
        #pragma unroll 8
        for (int c = 0; c < CH; ++c) acc = fmaf(wr[c], sb[c], acc);
        h_lds[tid] = fmaxf(acc, 0.0f);
    }
    __syncthreads();
    if (tid < PPB) {
        const int c = cbase + tid;
        float acc = b2[c];
        const float* __restrict__ wr = w2 + c * RCH;
        #pragma unroll 8
        for (int r = 0; r < RCH; ++r) acc = fmaf(wr[r], h_lds[r], acc);
        g_lds[tid] = 1.0f / (1.0f + expf(-acc));
    }
    __syncthreads();

    // ---------------- phase 3: scale + store ----------------
    f4* __restrict__ ob = (f4*)out + (size_t)(bid * PPB) * HWF4;
    #pragma unroll
    for (int q = 0; q < PPW; ++q) {
        const int pl = w * PPW + q;
        const f4* __restrict__ xp = xb + (size_t)pl * HWF4;
        f4* __restrict__ op = ob + (size_t)pl * HWF4;
        const float gg = g_lds[pl];

        #pragma unroll
        for (int st = 0; st < NREG; ++st) {
            f4 v = hold[q][st];
            v.x *= gg; v.y *= gg; v.z *= gg; v.w *= gg;
            __builtin_nontemporal_store(v, op + st * 64 + lane);
        }
        {
            f4 v = (pl < LDSPL) ? lds4[pl * 64 + lane]
                                : xp[NREG * 64 + lane];
            v.x *= gg; v.y *= gg; v.z *= gg; v.w *= gg;
            __builtin_nontemporal_store(v, op + NREG * 64 + lane);
        }
        #pragma unroll
        for (int st = NREG + 1; st < 12; ++st) {
            f4 v = xp[st * 64 + lane];
            v.x *= gg; v.y *= gg; v.z *= gg; v.w *= gg;
            __builtin_nontemporal_store(v, op + st * 64 + lane);
        }
        if (lane < 16) {
            f4 v = xp[768 + lane];
            v.x *= gg; v.y *= gg; v.z *= gg; v.w *= gg;
            __builtin_nontemporal_store(v, op + 768 + lane);
        }
    }
}

extern "C" void kernel_launch(void* const* d_in, const int* in_sizes, int n_in,
                              void* d_out, int out_size, void* d_ws, size_t ws_size,
                              hipStream_t stream) {
    const float* x  = (const float*)d_in[0];
    const float* w1 = (const float*)d_in[1];
    const float* b1 = (const float*)d_in[2];
    const float* w2 = (const float*)d_in[3];
    const float* b2 = (const float*)d_in[4];
    float* out  = (float*)d_out;
    float* s_ws = (float*)d_ws;          // NPLANES floats = 64 KB

    void* args[] = { (void*)&x, (void*)&w1, (void*)&b1, (void*)&w2,
                     (void*)&b2, (void*)&out, (void*)&s_ws };
    hipLaunchCooperativeKernel((const void*)se_fused,
                               dim3(NBLK), dim3(NTHR),
                               args, 0, stream);
}